// Round 11
// baseline (368.280 us; speedup 1.0000x reference)
//
#include <hip/hip_runtime.h>

// ---------------------------------------------------------------------------
// MultiHeadAttention: B=8, T=1024, E=256(head dim), H=8, TEMP=16
// 4 launches: prep_all | gemm_qkv(256x128, 512thr) |
//             flash attn (8 waves x 32 q-rows, 32x32x16 MFMA, QBLK=256) |
//             gemm_fc (64x64 tiles, BK=128)
// Attn r11: each wave owns 32 q-rows -> K/V tile read once per 32 q-rows
// (halves LDS-read traffic vs r10's 16 q-rows/wave). 32x32 layouts:
//   D: col=lane&31, row=(reg&3)+8*(reg>>2)+4*(lane>>5)   [m74/m101 verified]
//   A: row=lane&31, k=(lane>>5)*8+j ; B: col=lane&31, k=(lane>>5)*8+j
// launch_bounds minBlocks semantics: (512,4)->64 cap, (512,2)->128, (512,1)->256.
// ---------------------------------------------------------------------------

typedef __attribute__((ext_vector_type(8))) short bf16x8;
typedef __attribute__((ext_vector_type(4))) float f32x4;
typedef __attribute__((ext_vector_type(16))) float f32x16;
typedef __attribute__((ext_vector_type(4))) unsigned short u16x4;
typedef __attribute__((ext_vector_type(2))) unsigned int u32x2;
typedef __attribute__((ext_vector_type(4))) int i32x4;

#define B_DIM 8
#define T_DIM 1024
#define E_DIM 256
#define H_DIM 8

__device__ __forceinline__ unsigned short f2bf(float f) {
  unsigned u = __builtin_bit_cast(unsigned, f);
  u += 0x7FFFu + ((u >> 16) & 1u);   // RNE, finite values only
  return (unsigned short)(u >> 16);
}

__device__ __forceinline__ void gload_lds16(const void* g, void* l) {
  __builtin_amdgcn_global_load_lds(
      (const __attribute__((address_space(1))) void*)g,
      (__attribute__((address_space(3))) void*)l, 16, 0, 0);
}

__device__ __forceinline__ f32x4 mfma16(bf16x8 a, bf16x8 b, f32x4 c) {
  return __builtin_amdgcn_mfma_f32_16x16x32_bf16(a, b, c, 0, 0, 0);
}
__device__ __forceinline__ f32x16 mfma32(bf16x8 a, bf16x8 b, f32x16 c) {
  return __builtin_amdgcn_mfma_f32_32x32x16_bf16(a, b, c, 0, 0, 0);
}

// ---------- prep_all: xcast | mask bit-pack | weight transposes ------------
__global__ __launch_bounds__(256) void prep_all(
    const float* __restrict__ x, unsigned short* __restrict__ xbf,
    const int* __restrict__ mask, unsigned* __restrict__ mpk,
    const float* __restrict__ Wq, const float* __restrict__ Wk,
    const float* __restrict__ Wv, const float* __restrict__ Wfc,
    unsigned short* __restrict__ wall, unsigned short* __restrict__ wfcT) {
  __shared__ unsigned short tile[64][65];
  const int bid = blockIdx.x, tid = threadIdx.x;
  if (bid < 2048) {
    int i = bid * 256 + tid;
    f32x4 v = ((const f32x4*)x)[i];
    u16x4 o = { f2bf(v[0]), f2bf(v[1]), f2bf(v[2]), f2bf(v[3]) };
    ((u16x4*)xbf)[i] = o;
    return;
  }
  if (bid < 3072) {
    int i = (bid - 2048) * 256 + tid;   // 262144 u32 total
    const i32x4* src = (const i32x4*)(mask + (size_t)i * 32);
    unsigned v = 0;
#pragma unroll
    for (int j = 0; j < 8; ++j) {
      i32x4 a = src[j];
      v |= (a[0] != 0 ? 1u : 0u) << (j * 4 + 0);
      v |= (a[1] != 0 ? 1u : 0u) << (j * 4 + 1);
      v |= (a[2] != 0 ? 1u : 0u) << (j * 4 + 2);
      v |= (a[3] != 0 ? 1u : 0u) << (j * 4 + 3);
    }
    mpk[i] = v;
    return;
  }
  const int which = (bid - 3072) >> 7, bx = (bid - 3072) & 127;
  const float* in;
  unsigned short* out;
  int K, N, n0, k0;
  float scale;
  if (which < 3) {
    in = which == 0 ? Wq : (which == 1 ? Wk : Wv);
    out = wall + (size_t)which * 2048 * 256;
    K = 256; N = 2048; scale = which == 2 ? 1.0f : 0.25f;
    n0 = (bx & 31) * 64; k0 = (bx >> 5) * 64;
  } else {
    in = Wfc; out = wfcT; K = 2048; N = 256; scale = 1.0f;
    n0 = (bx & 3) * 64; k0 = (bx >> 2) * 64;
  }
#pragma unroll
  for (int p = 0; p < 16; ++p) {
    int i = p * 256 + tid;
    int r = i >> 6, c = i & 63;
    tile[c][r] = f2bf(in[(size_t)(k0 + r) * N + n0 + c] * scale);
  }
  __syncthreads();
#pragma unroll
  for (int p = 0; p < 16; ++p) {
    int i = p * 256 + tid;
    int r = i >> 6, c = i & 63;
    out[(size_t)(n0 + r) * K + k0 + c] = tile[r][c];
  }
}

// ---------------- merged QKV GEMM: 256x128 tiles, 512 thr ------------------
__global__ __launch_bounds__(512) void gemm_qkv(
    const unsigned short* __restrict__ A, const unsigned short* __restrict__ BT,
    unsigned short* __restrict__ qk, unsigned short* __restrict__ vout) {
  __shared__ unsigned short As[256 * 64];
  __shared__ unsigned short Bs[128 * 64];
  const int tid = threadIdx.x;
  const int w = tid >> 6, l = tid & 63, lg = l >> 4, lr = l & 15;
  const int tn = blockIdx.x * 128, tm = blockIdx.y * 256;
  const int wm = (w >> 1) * 64, wn = (w & 1) * 64;

  f32x4 acc[4][4];
#pragma unroll
  for (int i = 0; i < 4; ++i)
#pragma unroll
    for (int j = 0; j < 4; ++j) acc[i][j] = (f32x4){0.f, 0.f, 0.f, 0.f};

  for (int kt = 0; kt < 256; kt += 64) {
#pragma unroll
    for (int j = 0; j < 4; ++j) {
      int d = j * 8192 + tid * 16;
      int row = d >> 7, cb = d & 127;
      gload_lds16((const char*)(A + (size_t)(tm + row) * 256 + kt) + (cb ^ ((row & 7) << 4)),
                  (char*)As + d);
    }
#pragma unroll
    for (int j = 0; j < 2; ++j) {
      int d = j * 8192 + tid * 16;
      int row = d >> 7, cb = d & 127;
      gload_lds16((const char*)(BT + (size_t)(tn + row) * 256 + kt) + (cb ^ ((row & 7) << 4)),
                  (char*)Bs + d);
    }
    __syncthreads();
#pragma unroll
    for (int c = 0; c < 2; ++c) {
      bf16x8 af[4], bfr[4];
#pragma unroll
      for (int mf = 0; mf < 4; ++mf) {
        int row = wm + mf * 16 + lr;
        af[mf] = *(const bf16x8*)((const char*)As + row * 128 +
                                  ((c * 64 + lg * 16) ^ ((row & 7) << 4)));
      }
#pragma unroll
      for (int nf = 0; nf < 4; ++nf) {
        int row = wn + nf * 16 + lr;
        bfr[nf] = *(const bf16x8*)((const char*)Bs + row * 128 +
                                   ((c * 64 + lg * 16) ^ ((row & 7) << 4)));
      }
#pragma unroll
      for (int mf = 0; mf < 4; ++mf)
#pragma unroll
        for (int nf = 0; nf < 4; ++nf)
          acc[mf][nf] = mfma16(af[mf], bfr[nf], acc[mf][nf]);
    }
    __syncthreads();
  }

  if (tn < 4096) {  // Q/K region: [b][16 heads][t][e]
#pragma unroll
    for (int mf = 0; mf < 4; ++mf)
#pragma unroll
      for (int nf = 0; nf < 4; ++nf) {
        int col = tn + wn + nf * 16 + lr;
        int row0 = tm + wm + mf * 16 + lg * 4;
        int h16 = col >> 8, e = col & 255;
#pragma unroll
        for (int r = 0; r < 4; ++r) {
          int rowm = row0 + r;
          int bi = rowm >> 10, t = rowm & 1023;
          qk[(((size_t)bi * 16 + h16) * T_DIM + t) * E_DIM + e] = f2bf(acc[mf][nf][r]);
        }
      }
  } else {  // V region: [b][h][e][t], 4 consecutive t per u16x4
#pragma unroll
    for (int mf = 0; mf < 4; ++mf)
#pragma unroll
      for (int nf = 0; nf < 4; ++nf) {
        int col = tn + wn + nf * 16 + lr;
        int row0 = tm + wm + mf * 16 + lg * 4;
        int bi = row0 >> 10, t0 = row0 & 1023;
        int hh = (col >> 8) - 16, e = col & 255;
        u16x4 pk = { f2bf(acc[mf][nf][0]), f2bf(acc[mf][nf][1]),
                     f2bf(acc[mf][nf][2]), f2bf(acc[mf][nf][3]) };
        *(u16x4*)&vout[(((size_t)bi * H_DIM + hh) * E_DIM + e) * T_DIM + t0] = pk;
      }
  }
}

// ------------------------------ flash attention ----------------------------
// 256 blocks x 512 thr (8 waves x 32 q-rows = QBLK 256). KVBLK=64 single-buf.
// LDS = Kt 32K + Vt 32K + Pt 32K = 96KB. 32x32x16 MFMA for QK^T and PV.
// Swapped QK^T: S^T[kv][q]; lane owns q=l&31 for softmax (1 shfl_xor(32)).
// O fragment: col e=l&31, row q=crow(r,hi)=(r&3)+8*(r>>2)+4*hi.
__global__ __launch_bounds__(512, 1) void attn_kernel(
    const unsigned short* __restrict__ qkb, const unsigned short* __restrict__ vtb,
    const unsigned long long* __restrict__ mpk,
    unsigned short* __restrict__ aout) {
  __shared__ unsigned short Kt[64 * 256];   // [kv][e], swz (row&7)<<4 (32KB)
  __shared__ unsigned short Vt[256 * 64];   // [e][kv], swz (row&7)<<4 (32KB)
  __shared__ unsigned short Pt[8][32 * 64]; // per-wave P [q][kv], swz (32KB)

  const int tid = threadIdx.x;
  const int w = tid >> 6, l = tid & 63;
  const int q32 = l & 31, hi = l >> 5;
  // XCD swizzle: XCD x owns bh 8x..8x+7; 4 q-blocks of one bh consecutive.
  const int bid = blockIdx.x;
  const int x = bid & 7, j = bid >> 3;
  const int bh = x * 8 + (j >> 2), qt = j & 3;
  const int b = bh >> 3, h = bh & 7;

  const unsigned short* qg =
      qkb + (((size_t)b * 16 + h) * T_DIM + qt * 256) * E_DIM;
  const unsigned short* kg = qkb + (((size_t)b * 16 + 8 + h) * T_DIM) * E_DIM;
  const char* vgc = (const char*)(vtb + (size_t)bh * E_DIM * T_DIM);
  const unsigned long long* mrow =
      mpk + ((size_t)b * T_DIM + qt * 256 + w * 32 + q32) * 16;

  auto stageKV = [&](int kt) {
    const char* ksrc = (const char*)(kg + (size_t)(kt * 64) * E_DIM);
#pragma unroll
    for (int j2 = 0; j2 < 4; ++j2) {
      int d = j2 * 8192 + w * 1024 + l * 16;
      int row = d >> 9, cb = d & 511;
      gload_lds16(ksrc + row * 512 + (cb ^ ((row & 7) << 4)), (char*)Kt + d);
    }
#pragma unroll
    for (int j2 = 0; j2 < 4; ++j2) {
      int d = j2 * 8192 + w * 1024 + l * 16;
      int row = d >> 7, cb = d & 127;
      gload_lds16(vgc + (size_t)row * 2048 + kt * 128 + (cb ^ ((row & 7) << 4)),
                  (char*)Vt + d);
    }
  };

  stageKV(0);
  // Q fragments (B-operand): col q = w*32+q32, k-elems e = estep*16 + hi*8 + j
  bf16x8 qf[16];
  {
    const unsigned short* qrow = qg + (size_t)(w * 32 + q32) * E_DIM + hi * 8;
#pragma unroll
    for (int e = 0; e < 16; ++e) qf[e] = *(const bf16x8*)(qrow + e * 16);
  }

  f32x16 O[8];
#pragma unroll
  for (int i = 0; i < 8; ++i) O[i] = (f32x16)(0.f);
  float m_run = -INFINITY, l_run = 0.f;
  unsigned long long m_cur = mrow[0];

  for (int kt = 0; kt < 16; ++kt) {
    __syncthreads();   // stage(kt) landed (barrier drains vmcnt)
    unsigned long long m_next = (kt < 15) ? mrow[kt + 1] : 0ull;

    // ---- S^T = K * Q^T (32x32x16): D col=q32, row kv=crow(r,hi) (+32 for S1)
    f32x16 S0 = (f32x16)(0.f), S1 = (f32x16)(0.f);
    __builtin_amdgcn_s_setprio(1);
#pragma unroll
    for (int e = 0; e < 16; ++e) {
      int eb = e * 32 + hi * 16;
      bf16x8 a0 = *(const bf16x8*)((const char*)Kt + q32 * 512 +
                                   (eb ^ ((q32 & 7) << 4)));
      S0 = mfma32(a0, qf[e], S0);
      int row1 = 32 + q32;
      bf16x8 a1 = *(const bf16x8*)((const char*)Kt + row1 * 512 +
                                   (eb ^ ((row1 & 7) << 4)));
      S1 = mfma32(a1, qf[e], S1);
    }
    __builtin_amdgcn_s_setprio(0);

    // ---- mask + online softmax (lane owns q=w*32+q32)
    // value S0[r] is kv = (r&3)+8*(r>>2)+4*hi ; S1[r] is +32.
    float p0[16], p1[16];
    float tmax = -INFINITY;
    unsigned long long mm = m_cur >> (4 * hi);
#pragma unroll
    for (int r = 0; r < 16; ++r) {
      const int cr = (r & 3) + 8 * (r >> 2);
      float s0 = S0[r], s1 = S1[r];
      if ((mm >> cr) & 1ull) s0 = -INFINITY;
      if ((mm >> (cr + 32)) & 1ull) s1 = -INFINITY;
      p0[r] = s0; p1[r] = s1;
      tmax = fmaxf(tmax, fmaxf(s0, s1));
    }
    tmax = fmaxf(tmax, __shfl_xor(tmax, 32, 64));

    float m_old = m_run;
    int full = !__all(tmax - m_run <= 8.0f);
    if (full) m_run = fmaxf(m_run, tmax);
    float msafe = fmaxf(m_run, -1e30f);

    float rsum = 0.f;
#pragma unroll
    for (int r = 0; r < 16; ++r) {
      float e0 = __expf(p0[r] - msafe);
      float e1 = __expf(p1[r] - msafe);
      p0[r] = e0; p1[r] = e1;
      rsum += e0 + e1;
    }
    rsum += __shfl_xor(rsum, 32, 64);

    if (full) {
      float alpha = __expf(m_old - msafe);
      float av[16];
#pragma unroll
      for (int r = 0; r < 16; ++r)
        av[r] = __shfl(alpha, (r & 3) + 8 * (r >> 2) + 4 * hi, 64);
#pragma unroll
      for (int nf = 0; nf < 8; ++nf)
#pragma unroll
        for (int r = 0; r < 16; ++r) O[nf][r] *= av[r];
      l_run = l_run * alpha + rsum;
    } else {
      l_run += rsum;
    }

    // ---- write P (bf16) to per-wave LDS [32 q][64 kv], swz (q&7)<<4
    {
      char* pb = (char*)(Pt[w]) + q32 * 128;
      const int swz = (q32 & 7) << 4;
#pragma unroll
      for (int g = 0; g < 4; ++g) {
        u32x2 k0, k1;
        k0[0] = (unsigned)f2bf(p0[g * 4 + 0]) | ((unsigned)f2bf(p0[g * 4 + 1]) << 16);
        k0[1] = (unsigned)f2bf(p0[g * 4 + 2]) | ((unsigned)f2bf(p0[g * 4 + 3]) << 16);
        *(u32x2*)(pb + ((g * 16 + hi * 8) ^ swz)) = k0;
        k1[0] = (unsigned)f2bf(p1[g * 4 + 0]) | ((unsigned)f2bf(p1[g * 4 + 1]) << 16);
        k1[1] = (unsigned)f2bf(p1[g * 4 + 2]) | ((unsigned)f2bf(p1[g * 4 + 3]) << 16);
        *(u32x2*)(pb + ((g * 16 + hi * 8 + 64) ^ swz)) = k1;
      }
    }

    // ---- PV (32x32x16): O[q][e], A=P (row q, k=kv), B=V (col e, k=kv)
    __builtin_amdgcn_s_setprio(1);
    {
      const char* pbr = (const char*)(Pt[w]) + q32 * 128;
      const int swz = (q32 & 7) << 4;
      bf16x8 pa[4];
#pragma unroll
      for (int ks = 0; ks < 4; ++ks)
        pa[ks] = *(const bf16x8*)(pbr + ((ks * 32 + hi * 16) ^ swz));
#pragma unroll
      for (int nf = 0; nf < 8; ++nf) {
        int vrow = nf * 32 + q32;
        const char* vbase = (const char*)Vt + vrow * 128;
        const int vswz = (vrow & 7) << 4;
#pragma unroll
        for (int ks = 0; ks < 4; ++ks) {
          bf16x8 vb = *(const bf16x8*)(vbase + ((ks * 32 + hi * 16) ^ vswz));
          O[nf] = mfma32(pa[ks], vb, O[nf]);
        }
      }
    }
    __builtin_amdgcn_s_setprio(0);

    __syncthreads();   // all waves done reading Kt/Vt
    if (kt < 15) { stageKV(kt + 1); m_cur = m_next; }
  }

  // ---- epilogue: O/l (0 if fully masked), store bf16 [b][t][h*256+e]
  float linv = l_run > 0.f ? 1.f / l_run : 0.f;
  float lv[16];
#pragma unroll
  for (int r = 0; r < 16; ++r)
    lv[r] = __shfl(linv, (r & 3) + 8 * (r >> 2) + 4 * hi, 64);
  unsigned short* obase = aout + (size_t)(b * T_DIM) * 2048 + h * 256;
  const int q0 = qt * 256 + w * 32 + 4 * hi;
#pragma unroll
  for (int nf = 0; nf < 8; ++nf) {
#pragma unroll
    for (int r = 0; r < 16; ++r) {
      int qrow = q0 + (r & 3) + 8 * (r >> 2);
      obase[(size_t)qrow * 2048 + nf * 32 + q32] = f2bf(O[nf][r] * lv[r]);
    }
  }
}

// --------------- FC GEMM: 64x64 tiles, BK=128, 512 blocks ------------------
__global__ __launch_bounds__(256) void gemm_fc(
    const unsigned short* __restrict__ A, const unsigned short* __restrict__ BT,
    const float* __restrict__ bias, float* __restrict__ C) {
  __shared__ unsigned short As[64 * 128];
  __shared__ unsigned short Bs[64 * 128];
  const int tid = threadIdx.x;
  const int w = tid >> 6, l = tid & 63, lg = l >> 4, lr = l & 15;
  const int tn = blockIdx.x * 64, tm = blockIdx.y * 64;
  const int wm = (w >> 1) * 32, wn = (w & 1) * 32;

  f32x4 acc[2][2];
#pragma unroll
  for (int i = 0; i < 2; ++i)
#pragma unroll
    for (int j = 0; j < 2; ++j) acc[i][j] = (f32x4){0.f, 0.f, 0.f, 0.f};

  for (int kt = 0; kt < 2048; kt += 128) {
#pragma unroll
    for (int j = 0; j < 4; ++j) {
      int d = j * 4096 + tid * 16;
      int row = d >> 8, cb = d & 255;
      gload_lds16((const char*)(A + (size_t)(tm + row) * 2048 + kt) + (cb ^ ((row & 7) << 4)),
                  (char*)As + d);
    }
#pragma unroll
    for (int j = 0; j < 4; ++j) {
      int d = j * 4096 + tid * 16;
      int row = d >> 8, cb = d & 255;
      gload_lds16((const char*)(BT + (size_t)(tn + row) * 2048 + kt) + (cb ^ ((row & 7) << 4)),
                  (char*)Bs + d);
    }
    __syncthreads();
#pragma unroll
    for (int c = 0; c < 4; ++c) {
      bf16x8 af[2], bfr[2];
#pragma unroll
      for (int mf = 0; mf < 2; ++mf) {
        int row = wm + mf * 16 + lr;
        af[mf] = *(const bf16x8*)((const char*)As + row * 256 +
                                  ((c * 64 + lg * 16) ^ ((row & 7) << 4)));
      }
#pragma unroll
      for (int nf = 0; nf < 2; ++nf) {
        int row = wn + nf * 16 + lr;
        bfr[nf] = *(const bf16x8*)((const char*)Bs + row * 256 +
                                   ((c * 64 + lg * 16) ^ ((row & 7) << 4)));
      }
#pragma unroll
      for (int mf = 0; mf < 2; ++mf)
#pragma unroll
        for (int nf = 0; nf < 2; ++nf)
          acc[mf][nf] = mfma16(af[mf], bfr[nf], acc[mf][nf]);
    }
    __syncthreads();
  }

#pragma unroll
  for (int mf = 0; mf < 2; ++mf)
#pragma unroll
    for (int nf = 0; nf < 2; ++nf) {
      int col = tn + wn + nf * 16 + lr;
      int row0 = tm + wm + mf * 16 + lg * 4;
      float bv = bias[col];
#pragma unroll
      for (int r = 0; r < 4; ++r)
        C[(size_t)(row0 + r) * 256 + col] = acc[mf][nf][r] + bv;
    }
}

// ------------------------------- launcher ----------------------------------
extern "C" void kernel_launch(void* const* d_in, const int* in_sizes, int n_in,
                              void* d_out, int out_size, void* d_ws, size_t ws_size,
                              hipStream_t stream) {
  (void)in_sizes; (void)n_in; (void)out_size; (void)ws_size;
  const float* x    = (const float*)d_in[0];
  const float* Wq   = (const float*)d_in[1];
  const float* Wk   = (const float*)d_in[2];
  const float* Wv   = (const float*)d_in[3];
  const float* Wfc  = (const float*)d_in[4];
  const float* bfc  = (const float*)d_in[5];
  const int* mask   = (const int*)d_in[6];
  float* out = (float*)d_out;

  char* ws = (char*)d_ws;
  unsigned short* xbf  = (unsigned short*)(ws + 0);          //   4 MB [8192][256]
  unsigned short* qkb  = (unsigned short*)(ws + 4194304);    //  64 MB [b][16][t][e]
  unsigned short* vbuf = (unsigned short*)(ws + 71303168);   //  32 MB [b][h][e][t]
  unsigned short* abuf = (unsigned short*)(ws + 104857600);  //  32 MB [8192][2048]
  unsigned short* wall = (unsigned short*)(ws + 138412032);  //   3 MB [6144][256]
  unsigned short* wfcT = (unsigned short*)(ws + 141557760);  //   1 MB [256][2048]
  unsigned*       mpk  = (unsigned*)(ws + 142606336);        //   1 MB packed mask

  prep_all<<<3584, 256, 0, stream>>>(x, xbf, mask, mpk, Wq, Wk, Wv, Wfc,
                                     wall, wfcT);
  gemm_qkv<<<dim3(48, 32), 512, 0, stream>>>(xbf, wall, qkb, vbuf);
  attn_kernel<<<256, 512, 0, stream>>>(qkb, vbuf,
                                       (const unsigned long long*)mpk, abuf);
  gemm_fc<<<dim3(4, 128), 256, 0, stream>>>(abuf, wfcT, bfc, out);
}

// Round 13
// 331.708 us; speedup vs baseline: 1.1103x; 1.1103x over previous
//
#include <hip/hip_runtime.h>

// ---------------------------------------------------------------------------
// MultiHeadAttention: B=8, T=1024, E=256(head dim), H=8, TEMP=16
// 4 launches: prep_all | gemm_qkv(256x128, 512thr) |
//             flash attn (4 waves x 32 q-rows, 16x16 MFMA, 512-reg budget) |
//             gemm_fc (64x64 tiles, BK=128)
// Attn r12: 256 thr / 4 waves, each wave 32 q-rows (2 groups of 16).
// Each K/V LDS fragment read feeds BOTH q-groups -> per-CU LDS read traffic
// halves vs r10 (the measured bottleneck: ~77us of 127us).
// __launch_bounds__(256,1): 1 wave/SIMD -> 512-reg budget, no spill at ~300.
// launch_bounds minBlocks semantics (established r6/r7/r8): cap = 512/(waves/SIMD).
// ---------------------------------------------------------------------------

typedef __attribute__((ext_vector_type(8))) short bf16x8;
typedef __attribute__((ext_vector_type(4))) float f32x4;
typedef __attribute__((ext_vector_type(4))) unsigned short u16x4;
typedef __attribute__((ext_vector_type(2))) unsigned int u32x2;
typedef __attribute__((ext_vector_type(4))) int i32x4;

#define B_DIM 8
#define T_DIM 1024
#define E_DIM 256
#define H_DIM 8

__device__ __forceinline__ unsigned short f2bf(float f) {
  unsigned u = __builtin_bit_cast(unsigned, f);
  u += 0x7FFFu + ((u >> 16) & 1u);   // RNE, finite values only
  return (unsigned short)(u >> 16);
}

__device__ __forceinline__ void gload_lds16(const void* g, void* l) {
  __builtin_amdgcn_global_load_lds(
      (const __attribute__((address_space(1))) void*)g,
      (__attribute__((address_space(3))) void*)l, 16, 0, 0);
}

__device__ __forceinline__ f32x4 mfma16(bf16x8 a, bf16x8 b, f32x4 c) {
  return __builtin_amdgcn_mfma_f32_16x16x32_bf16(a, b, c, 0, 0, 0);
}

// ---------- prep_all: xcast | mask bit-pack | weight transposes ------------
__global__ __launch_bounds__(256) void prep_all(
    const float* __restrict__ x, unsigned short* __restrict__ xbf,
    const int* __restrict__ mask, unsigned* __restrict__ mpk,
    const float* __restrict__ Wq, const float* __restrict__ Wk,
    const float* __restrict__ Wv, const float* __restrict__ Wfc,
    unsigned short* __restrict__ wall, unsigned short* __restrict__ wfcT) {
  __shared__ unsigned short tile[64][65];
  const int bid = blockIdx.x, tid = threadIdx.x;
  if (bid < 2048) {
    int i = bid * 256 + tid;
    f32x4 v = ((const f32x4*)x)[i];
    u16x4 o = { f2bf(v[0]), f2bf(v[1]), f2bf(v[2]), f2bf(v[3]) };
    ((u16x4*)xbf)[i] = o;
    return;
  }
  if (bid < 3072) {
    int i = (bid - 2048) * 256 + tid;   // 262144 u32 total
    const i32x4* src = (const i32x4*)(mask + (size_t)i * 32);
    unsigned v = 0;
#pragma unroll
    for (int j = 0; j < 8; ++j) {
      i32x4 a = src[j];
      v |= (a[0] != 0 ? 1u : 0u) << (j * 4 + 0);
      v |= (a[1] != 0 ? 1u : 0u) << (j * 4 + 1);
      v |= (a[2] != 0 ? 1u : 0u) << (j * 4 + 2);
      v |= (a[3] != 0 ? 1u : 0u) << (j * 4 + 3);
    }
    mpk[i] = v;
    return;
  }
  const int which = (bid - 3072) >> 7, bx = (bid - 3072) & 127;
  const float* in;
  unsigned short* out;
  int K, N, n0, k0;
  float scale;
  if (which < 3) {
    in = which == 0 ? Wq : (which == 1 ? Wk : Wv);
    out = wall + (size_t)which * 2048 * 256;
    K = 256; N = 2048; scale = which == 2 ? 1.0f : 0.25f;
    n0 = (bx & 31) * 64; k0 = (bx >> 5) * 64;
  } else {
    in = Wfc; out = wfcT; K = 2048; N = 256; scale = 1.0f;
    n0 = (bx & 3) * 64; k0 = (bx >> 2) * 64;
  }
#pragma unroll
  for (int p = 0; p < 16; ++p) {
    int i = p * 256 + tid;
    int r = i >> 6, c = i & 63;
    tile[c][r] = f2bf(in[(size_t)(k0 + r) * N + n0 + c] * scale);
  }
  __syncthreads();
#pragma unroll
  for (int p = 0; p < 16; ++p) {
    int i = p * 256 + tid;
    int r = i >> 6, c = i & 63;
    out[(size_t)(n0 + r) * K + k0 + c] = tile[r][c];
  }
}

// ---------------- merged QKV GEMM: 256x128 tiles, 512 thr ------------------
__global__ __launch_bounds__(512) void gemm_qkv(
    const unsigned short* __restrict__ A, const unsigned short* __restrict__ BT,
    unsigned short* __restrict__ qk, unsigned short* __restrict__ vout) {
  __shared__ unsigned short As[256 * 64];
  __shared__ unsigned short Bs[128 * 64];
  const int tid = threadIdx.x;
  const int w = tid >> 6, l = tid & 63, lg = l >> 4, lr = l & 15;
  const int tn = blockIdx.x * 128, tm = blockIdx.y * 256;
  const int wm = (w >> 1) * 64, wn = (w & 1) * 64;

  f32x4 acc[4][4];
#pragma unroll
  for (int i = 0; i < 4; ++i)
#pragma unroll
    for (int j = 0; j < 4; ++j) acc[i][j] = (f32x4){0.f, 0.f, 0.f, 0.f};

  for (int kt = 0; kt < 256; kt += 64) {
#pragma unroll
    for (int j = 0; j < 4; ++j) {
      int d = j * 8192 + tid * 16;
      int row = d >> 7, cb = d & 127;
      gload_lds16((const char*)(A + (size_t)(tm + row) * 256 + kt) + (cb ^ ((row & 7) << 4)),
                  (char*)As + d);
    }
#pragma unroll
    for (int j = 0; j < 2; ++j) {
      int d = j * 8192 + tid * 16;
      int row = d >> 7, cb = d & 127;
      gload_lds16((const char*)(BT + (size_t)(tn + row) * 256 + kt) + (cb ^ ((row & 7) << 4)),
                  (char*)Bs + d);
    }
    __syncthreads();
#pragma unroll
    for (int c = 0; c < 2; ++c) {
      bf16x8 af[4], bfr[4];
#pragma unroll
      for (int mf = 0; mf < 4; ++mf) {
        int row = wm + mf * 16 + lr;
        af[mf] = *(const bf16x8*)((const char*)As + row * 128 +
                                  ((c * 64 + lg * 16) ^ ((row & 7) << 4)));
      }
#pragma unroll
      for (int nf = 0; nf < 4; ++nf) {
        int row = wn + nf * 16 + lr;
        bfr[nf] = *(const bf16x8*)((const char*)Bs + row * 128 +
                                   ((c * 64 + lg * 16) ^ ((row & 7) << 4)));
      }
#pragma unroll
      for (int mf = 0; mf < 4; ++mf)
#pragma unroll
        for (int nf = 0; nf < 4; ++nf)
          acc[mf][nf] = mfma16(af[mf], bfr[nf], acc[mf][nf]);
    }
    __syncthreads();
  }

  if (tn < 4096) {  // Q/K region: [b][16 heads][t][e]
#pragma unroll
    for (int mf = 0; mf < 4; ++mf)
#pragma unroll
      for (int nf = 0; nf < 4; ++nf) {
        int col = tn + wn + nf * 16 + lr;
        int row0 = tm + wm + mf * 16 + lg * 4;
        int h16 = col >> 8, e = col & 255;
#pragma unroll
        for (int r = 0; r < 4; ++r) {
          int rowm = row0 + r;
          int bi = rowm >> 10, t = rowm & 1023;
          qk[(((size_t)bi * 16 + h16) * T_DIM + t) * E_DIM + e] = f2bf(acc[mf][nf][r]);
        }
      }
  } else {  // V region: [b][h][e][t], 4 consecutive t per u16x4
#pragma unroll
    for (int mf = 0; mf < 4; ++mf)
#pragma unroll
      for (int nf = 0; nf < 4; ++nf) {
        int col = tn + wn + nf * 16 + lr;
        int row0 = tm + wm + mf * 16 + lg * 4;
        int bi = row0 >> 10, t0 = row0 & 1023;
        int hh = (col >> 8) - 16, e = col & 255;
        u16x4 pk = { f2bf(acc[mf][nf][0]), f2bf(acc[mf][nf][1]),
                     f2bf(acc[mf][nf][2]), f2bf(acc[mf][nf][3]) };
        *(u16x4*)&vout[(((size_t)bi * H_DIM + hh) * E_DIM + e) * T_DIM + t0] = pk;
      }
  }
}

// ------------------------------ flash attention ----------------------------
// 512 blocks x 256 thr (4 waves). QBLK=128: wave w owns q-rows w*32..w*32+31
// as 2 groups of 16. KVBLK=64 single-buf. LDS = Kt 32K + Vt 32K + Pt 16K.
// Each K/V fragment read feeds both q-groups (2 MFMAs per read) -> per-CU
// LDS traffic ~half of r10. Swapped QK^T: S^T[kv][q], lane (l&15)=q.
__global__ __launch_bounds__(256, 1) void attn_kernel(
    const unsigned short* __restrict__ qkb, const unsigned short* __restrict__ vtb,
    const unsigned long long* __restrict__ mpk,
    unsigned short* __restrict__ aout) {
  __shared__ unsigned short Kt[64 * 256];   // [kv][e], swz (row&7)<<4 (32KB)
  __shared__ unsigned short Vt[256 * 64];   // [e][kv], swz (row&7)<<4 (32KB)
  __shared__ unsigned short Pt[4][32 * 64]; // per-wave P [32q][64kv]   (16KB)

  const int tid = threadIdx.x;
  const int w = tid >> 6, l = tid & 63, lg = l >> 4, lr = l & 15;
  // XCD swizzle: XCD x owns bh 8x..8x+7; q-tiles of one bh consecutive.
  const int bid = blockIdx.x;
  const int x = bid & 7, j = bid >> 3;
  const int bh = x * 8 + (j >> 3), qt = j & 7;
  const int b = bh >> 3, h = bh & 7;

  const unsigned short* qg =
      qkb + (((size_t)b * 16 + h) * T_DIM + qt * 128) * E_DIM;
  const unsigned short* kg = qkb + (((size_t)b * 16 + 8 + h) * T_DIM) * E_DIM;
  const char* vgc = (const char*)(vtb + (size_t)bh * E_DIM * T_DIM);
  // mask rows for this lane's two q rows (16 u64 per row)
  const unsigned long long* mrow0 =
      mpk + ((size_t)b * T_DIM + qt * 128 + w * 32 + lr) * 16;
  const unsigned long long* mrow1 = mrow0 + 16 * 16;

  // stage K/V tile kt (64 kv); 4 waves cooperate, 8 passes each of 4KB
  auto stageKV = [&](int kt) {
    const char* ksrc = (const char*)(kg + (size_t)(kt * 64) * E_DIM);
#pragma unroll
    for (int p = 0; p < 8; ++p) {
      int d = p * 4096 + tid * 16;
      int row = d >> 9, cb = d & 511;
      gload_lds16(ksrc + row * 512 + (cb ^ ((row & 7) << 4)), (char*)Kt + d);
    }
#pragma unroll
    for (int p = 0; p < 8; ++p) {
      int d = p * 4096 + tid * 16;
      int row = d >> 7, cb = d & 127;
      gload_lds16(vgc + (size_t)row * 2048 + kt * 128 + (cb ^ ((row & 7) << 4)),
                  (char*)Vt + d);
    }
  };

  stageKV(0);
  // Q fragments: group g covers rows w*32 + g*16 + lr, k = c*32 + lg*8
  bf16x8 qf[2][8];
#pragma unroll
  for (int g = 0; g < 2; ++g) {
    const unsigned short* qrow =
        qg + (size_t)(w * 32 + g * 16 + lr) * E_DIM + lg * 8;
#pragma unroll
    for (int c = 0; c < 8; ++c) qf[g][c] = *(const bf16x8*)(qrow + c * 32);
  }

  f32x4 O[2][16];
#pragma unroll
  for (int g = 0; g < 2; ++g)
#pragma unroll
    for (int i = 0; i < 16; ++i) O[g][i] = (f32x4){0.f, 0.f, 0.f, 0.f};
  float m_run0 = -INFINITY, m_run1 = -INFINITY;
  float l_run0 = 0.f, l_run1 = 0.f;
  unsigned long long mc0 = mrow0[0], mc1 = mrow1[0];

  for (int kt = 0; kt < 16; ++kt) {
    __syncthreads();   // stage(kt) landed (barrier drains vmcnt)
    unsigned long long mn0 = (kt < 15) ? mrow0[kt + 1] : 0ull;
    unsigned long long mn1 = (kt < 15) ? mrow1[kt + 1] : 0ull;

    // ---- S^T = K * Q^T for both q-groups; each K-frag read feeds 2 MFMAs
    f32x4 S0[4], S1[4];
#pragma unroll
    for (int i = 0; i < 4; ++i) {
      S0[i] = (f32x4){0.f, 0.f, 0.f, 0.f};
      S1[i] = (f32x4){0.f, 0.f, 0.f, 0.f};
    }
    __builtin_amdgcn_s_setprio(1);
#pragma unroll
    for (int kvf = 0; kvf < 4; ++kvf) {
      int row = kvf * 16 + lr;
      const char* abase = (const char*)Kt + row * 512;
      int swz = (row & 7) << 4;
#pragma unroll
      for (int c = 0; c < 8; ++c) {
        bf16x8 a = *(const bf16x8*)(abase + ((c * 64 + lg * 16) ^ swz));
        S0[kvf] = mfma16(a, qf[0][c], S0[kvf]);
        S1[kvf] = mfma16(a, qf[1][c], S1[kvf]);
      }
    }
    __builtin_amdgcn_s_setprio(0);

    // ---- mask + online softmax (lane owns q0 = w*32+lr, q1 = +16)
    float p0[4][4], p1[4][4];
    float tmax0 = -INFINITY, tmax1 = -INFINITY;
#pragma unroll
    for (int kvf = 0; kvf < 4; ++kvf) {
      unsigned nib0 = (unsigned)(mc0 >> (kvf * 16 + lg * 4)) & 0xFu;
      unsigned nib1 = (unsigned)(mc1 >> (kvf * 16 + lg * 4)) & 0xFu;
#pragma unroll
      for (int r = 0; r < 4; ++r) {
        float s0 = S0[kvf][r], s1 = S1[kvf][r];
        if (nib0 & (1u << r)) s0 = -INFINITY;
        if (nib1 & (1u << r)) s1 = -INFINITY;
        p0[kvf][r] = s0; p1[kvf][r] = s1;
        tmax0 = fmaxf(tmax0, s0); tmax1 = fmaxf(tmax1, s1);
      }
    }
    tmax0 = fmaxf(tmax0, __shfl_xor(tmax0, 16, 64));
    tmax0 = fmaxf(tmax0, __shfl_xor(tmax0, 32, 64));
    tmax1 = fmaxf(tmax1, __shfl_xor(tmax1, 16, 64));
    tmax1 = fmaxf(tmax1, __shfl_xor(tmax1, 32, 64));

    // defer-max (T13): joint condition for both groups (wave-uniform branch)
    float m_old0 = m_run0, m_old1 = m_run1;
    int full = !__all(fmaxf(tmax0 - m_run0, tmax1 - m_run1) <= 8.0f);
    if (full) { m_run0 = fmaxf(m_run0, tmax0); m_run1 = fmaxf(m_run1, tmax1); }
    float ms0 = fmaxf(m_run0, -1e30f), ms1 = fmaxf(m_run1, -1e30f);

    float rs0 = 0.f, rs1 = 0.f;
#pragma unroll
    for (int kvf = 0; kvf < 4; ++kvf)
#pragma unroll
      for (int r = 0; r < 4; ++r) {
        float e0 = __expf(p0[kvf][r] - ms0);
        float e1 = __expf(p1[kvf][r] - ms1);
        p0[kvf][r] = e0; p1[kvf][r] = e1;
        rs0 += e0; rs1 += e1;
      }
    rs0 += __shfl_xor(rs0, 16, 64);
    rs0 += __shfl_xor(rs0, 32, 64);
    rs1 += __shfl_xor(rs1, 16, 64);
    rs1 += __shfl_xor(rs1, 32, 64);

    if (full) {
      float a0 = __expf(m_old0 - ms0), a1 = __expf(m_old1 - ms1);
      float av0[4], av1[4];
#pragma unroll
      for (int r = 0; r < 4; ++r) {
        av0[r] = __shfl(a0, lg * 4 + r, 64);
        av1[r] = __shfl(a1, lg * 4 + r, 64);
      }
#pragma unroll
      for (int nf = 0; nf < 16; ++nf)
#pragma unroll
        for (int r = 0; r < 4; ++r) {
          O[0][nf][r] *= av0[r];
          O[1][nf][r] *= av1[r];
        }
      l_run0 = l_run0 * a0 + rs0;
      l_run1 = l_run1 * a1 + rs1;
    } else {
      l_run0 += rs0;
      l_run1 += rs1;
    }

    // ---- write P (bf16) for both groups to per-wave LDS, swz (lr&7)<<4
    {
      const int swz = (lr & 7) << 4;
#pragma unroll
      for (int g = 0; g < 2; ++g) {
        char* pb = (char*)(Pt[w]) + (g * 16 + lr) * 128;
        const float(*pg)[4] = g ? p1 : p0;
#pragma unroll
        for (int kvf = 0; kvf < 4; ++kvf) {
          u32x2 pk;
          pk[0] = (unsigned)f2bf(pg[kvf][0]) | ((unsigned)f2bf(pg[kvf][1]) << 16);
          pk[1] = (unsigned)f2bf(pg[kvf][2]) | ((unsigned)f2bf(pg[kvf][3]) << 16);
          *(u32x2*)(pb + ((kvf * 32 + lg * 8) ^ swz)) = pk;
        }
      }
    }

    // ---- PV: each V-frag read feeds both q-groups
    __builtin_amdgcn_s_setprio(1);
    {
      const int swz = (lr & 7) << 4;
      bf16x8 pa0[2], pa1[2];
#pragma unroll
      for (int c2 = 0; c2 < 2; ++c2) {
        pa0[c2] = *(const bf16x8*)((const char*)(Pt[w]) + (0 * 16 + lr) * 128 +
                                   ((c2 * 64 + lg * 16) ^ swz));
        pa1[c2] = *(const bf16x8*)((const char*)(Pt[w]) + (1 * 16 + lr) * 128 +
                                   ((c2 * 64 + lg * 16) ^ swz));
      }
#pragma unroll
      for (int c2 = 0; c2 < 2; ++c2) {
#pragma unroll
        for (int nf = 0; nf < 16; ++nf) {
          int vrow = nf * 16 + lr;
          bf16x8 vb = *(const bf16x8*)((const char*)Vt + vrow * 128 +
                                       ((c2 * 64 + lg * 16) ^ ((vrow & 7) << 4)));
          O[0][nf] = mfma16(pa0[c2], vb, O[0][nf]);
          O[1][nf] = mfma16(pa1[c2], vb, O[1][nf]);
        }
      }
    }
    __builtin_amdgcn_s_setprio(0);

    __syncthreads();   // all waves done reading Kt/Vt
    if (kt < 15) { stageKV(kt + 1); mc0 = mn0; mc1 = mn1; }
  }

  // ---- epilogue: O/l (0 if fully masked), store bf16 [b][t][h*256+e]
  float li0 = l_run0 > 0.f ? 1.f / l_run0 : 0.f;
  float li1 = l_run1 > 0.f ? 1.f / l_run1 : 0.f;
  float lv0[4], lv1[4];
#pragma unroll
  for (int r = 0; r < 4; ++r) {
    lv0[r] = __shfl(li0, lg * 4 + r, 64);
    lv1[r] = __shfl(li1, lg * 4 + r, 64);
  }
  unsigned short* obase = aout + (size_t)(b * T_DIM) * 2048 + h * 256;
  const int q0 = qt * 128 + w * 32 + lg * 4;
#pragma unroll
  for (int nf = 0; nf < 16; ++nf) {
#pragma unroll
    for (int r = 0; r < 4; ++r) {
      obase[(size_t)(q0 + r) * 2048 + nf * 16 + lr] = f2bf(O[0][nf][r] * lv0[r]);
      obase[(size_t)(q0 + 16 + r) * 2048 + nf * 16 + lr] = f2bf(O[1][nf][r] * lv1[r]);
    }
  }
}

// --------------- FC GEMM: 64x64 tiles, BK=128, 512 blocks ------------------
__global__ __launch_bounds__(256) void gemm_fc(
    const unsigned short* __restrict__ A, const unsigned short* __restrict__ BT,
    const float* __restrict__ bias, float* __restrict__ C) {
  __shared__ unsigned short As[64 * 128];
  __shared__ unsigned short Bs[64 * 128];
  const int tid = threadIdx.x;
  const int w = tid >> 6, l = tid & 63, lg = l >> 4, lr = l & 15;
  const int tn = blockIdx.x * 64, tm = blockIdx.y * 64;
  const int wm = (w >> 1) * 32, wn = (w & 1) * 32;

  f32x4 acc[2][2];
#pragma unroll
  for (int i = 0; i < 2; ++i)
#pragma unroll
    for (int j = 0; j < 2; ++j) acc[i][j] = (f32x4){0.f, 0.f, 0.f, 0.f};

  for (int kt = 0; kt < 2048; kt += 128) {
#pragma unroll
    for (int j = 0; j < 4; ++j) {
      int d = j * 4096 + tid * 16;
      int row = d >> 8, cb = d & 255;
      gload_lds16((const char*)(A + (size_t)(tm + row) * 2048 + kt) + (cb ^ ((row & 7) << 4)),
                  (char*)As + d);
    }
#pragma unroll
    for (int j = 0; j < 4; ++j) {
      int d = j * 4096 + tid * 16;
      int row = d >> 8, cb = d & 255;
      gload_lds16((const char*)(BT + (size_t)(tn + row) * 2048 + kt) + (cb ^ ((row & 7) << 4)),
                  (char*)Bs + d);
    }
    __syncthreads();
#pragma unroll
    for (int c = 0; c < 4; ++c) {
      bf16x8 af[2], bfr[2];
#pragma unroll
      for (int mf = 0; mf < 2; ++mf) {
        int row = wm + mf * 16 + lr;
        af[mf] = *(const bf16x8*)((const char*)As + row * 256 +
                                  ((c * 64 + lg * 16) ^ ((row & 7) << 4)));
      }
#pragma unroll
      for (int nf = 0; nf < 2; ++nf) {
        int row = wn + nf * 16 + lr;
        bfr[nf] = *(const bf16x8*)((const char*)Bs + row * 256 +
                                   ((c * 64 + lg * 16) ^ ((row & 7) << 4)));
      }
#pragma unroll
      for (int mf = 0; mf < 2; ++mf)
#pragma unroll
        for (int nf = 0; nf < 2; ++nf)
          acc[mf][nf] = mfma16(af[mf], bfr[nf], acc[mf][nf]);
    }
    __syncthreads();
  }

#pragma unroll
  for (int mf = 0; mf < 2; ++mf)
#pragma unroll
    for (int nf = 0; nf < 2; ++nf) {
      int col = tn + wn + nf * 16 + lr;
      int row0 = tm + wm + mf * 16 + lg * 4;
      float bv = bias[col];
#pragma unroll
      for (int r = 0; r < 4; ++r)
        C[(size_t)(row0 + r) * 256 + col] = acc[mf][nf][r] + bv;
    }
}

// ------------------------------- launcher ----------------------------------
extern "C" void kernel_launch(void* const* d_in, const int* in_sizes, int n_in,
                              void* d_out, int out_size, void* d_ws, size_t ws_size,
                              hipStream_t stream) {
  (void)in_sizes; (void)n_in; (void)out_size; (void)ws_size;
  const float* x    = (const float*)d_in[0];
  const float* Wq   = (const float*)d_in[1];
  const float* Wk   = (const float*)d_in[2];
  const float* Wv   = (const float*)d_in[3];
  const float* Wfc  = (const float*)d_in[4];
  const float* bfc  = (const float*)d_in[5];
  const int* mask   = (const int*)d_in[6];
  float* out = (float*)d_out;

  char* ws = (char*)d_ws;
  unsigned short* xbf  = (unsigned short*)(ws + 0);          //   4 MB [8192][256]
  unsigned short* qkb  = (unsigned short*)(ws + 4194304);    //  64 MB [b][16][t][e]
  unsigned short* vbuf = (unsigned short*)(ws + 71303168);   //  32 MB [b][h][e][t]
  unsigned short* abuf = (unsigned short*)(ws + 104857600);  //  32 MB [8192][2048]
  unsigned short* wall = (unsigned short*)(ws + 138412032);  //   3 MB [6144][256]
  unsigned short* wfcT = (unsigned short*)(ws + 141557760);  //   1 MB [256][2048]
  unsigned*       mpk  = (unsigned*)(ws + 142606336);        //   1 MB packed mask

  prep_all<<<3584, 256, 0, stream>>>(x, xbf, mask, mpk, Wq, Wk, Wv, Wfc,
                                     wall, wfcT);
  gemm_qkv<<<dim3(48, 32), 512, 0, stream>>>(xbf, wall, qkb, vbuf);
  attn_kernel<<<512, 256, 0, stream>>>(qkb, vbuf,
                                       (const unsigned long long*)mpk, abuf);
  gemm_fc<<<dim3(4, 128), 256, 0, stream>>>(abuf, wfcT, bfc, out);
}